// Round 1
// baseline (446.370 us; speedup 1.0000x reference)
//
#include <hip/hip_runtime.h>
#include <math.h>

// Problem constants (match reference)
#define DIM_EMB 1024
#define TIMESTEP 4096
#define BATCH 16

// out[b,t,c] = x[b,t,c] * sqrt(D) + pe[t,c]
// pe[t,c] = sin(t * 10000^(-2c/D)) for even c, cos(...) for odd c.
// Memory-bound: 512 MiB traffic. One block per t-row; each thread computes
// 4 PE values once (float4 slot) and loops over the 16 batches reusing them.
__global__ __launch_bounds__(256)
void Pos_embedding_39161511805397_kernel(const float* __restrict__ x,
                                         float* __restrict__ out) {
    const int t   = blockIdx.x;       // 0..TIMESTEP-1
    const int tid = threadIdx.x;      // 0..255
    const int c0  = tid << 2;         // column of .x component (even)

    const float pos = (float)t;
    // inv(c) = 10000^(-2c/D) = exp2( -log2(10000)/ (D/2) * c )
    const float k = -13.287712379549449f / 512.0f;  // -log2(10000) / (D/2)
    const float a0 = pos * exp2f(k * (float)(c0 + 0));
    const float a1 = pos * exp2f(k * (float)(c0 + 1));
    const float a2 = pos * exp2f(k * (float)(c0 + 2));
    const float a3 = pos * exp2f(k * (float)(c0 + 3));

    float4 pe;
    pe.x = sinf(a0);   // even col
    pe.y = cosf(a1);   // odd col
    pe.z = sinf(a2);   // even col
    pe.w = cosf(a3);   // odd col

    const float s = 32.0f;  // sqrt(1024), exact

    const float4* __restrict__ xv = (const float4*)x;
    float4* __restrict__ ov       = (float4*)out;

    size_t idx = ((size_t)t * DIM_EMB + (size_t)c0) >> 2;          // float4 units
    const size_t stride = ((size_t)TIMESTEP * DIM_EMB) >> 2;       // per batch

    #pragma unroll
    for (int b = 0; b < BATCH; ++b) {
        float4 v = xv[idx];
        v.x = fmaf(v.x, s, pe.x);
        v.y = fmaf(v.y, s, pe.y);
        v.z = fmaf(v.z, s, pe.z);
        v.w = fmaf(v.w, s, pe.w);
        ov[idx] = v;
        idx += stride;
    }
}

extern "C" void kernel_launch(void* const* d_in, const int* in_sizes, int n_in,
                              void* d_out, int out_size, void* d_ws, size_t ws_size,
                              hipStream_t stream) {
    const float* x = (const float*)d_in[0];
    float* out     = (float*)d_out;
    dim3 grid(TIMESTEP);
    dim3 block(256);
    Pos_embedding_39161511805397_kernel<<<grid, block, 0, stream>>>(x, out);
}